// Round 6
// baseline (1354.018 us; speedup 1.0000x reference)
//
#include <hip/hip_runtime.h>
#include <math.h>

#define NB   256
#define LSEQ 1800
#define NF   50
#define NE   4
#define NH   32
#define G3   96
#define ND   64
#define NHU  32
#define CHUNK 72
#define TBLK  8
#define NCHUNK (LSEQ / CHUNK)   // 25
#define NBLK   (CHUNK / TBLK)   // 9

typedef float v2f __attribute__((ext_vector_type(2)));

__device__ __forceinline__ v2f v2fma(v2f a, v2f b, v2f c) {
    return __builtin_elementwise_fma(a, b, c);
}
__device__ __forceinline__ v2f mkv2(float a, float b) { v2f t; t.x = a; t.y = b; return t; }
__device__ __forceinline__ v2f splat2(float s) { v2f t; t.x = s; t.y = s; return t; }

// ---------------------------------------------------------------------------
// Kernel 1: fold input projection into layer-0 input weights.
// Cg[e][f][g] = sum_d Wih0[e][g][d] * W_in[d][f]
// ---------------------------------------------------------------------------
__global__ void compute_C_kernel(const float* __restrict__ Wih0,
                                 const float* __restrict__ W_in,
                                 float* __restrict__ Cg) {
    int e = blockIdx.x;
    for (int idx = threadIdx.x; idx < NF * G3; idx += blockDim.x) {
        int f = idx / G3;
        int g = idx - f * G3;
        const float* wr = Wih0 + ((size_t)e * G3 + g) * ND;
        float s = 0.f;
        #pragma unroll 8
        for (int d = 0; d < ND; d++) s += wr[d] * W_in[d * NF + f];
        Cg[(size_t)e * NF * G3 + idx] = s;
    }
}

// Fast transcendentals on v_exp_f32 / v_rcp_f32.
__device__ __forceinline__ float fsig(float x) {
    float e = __builtin_amdgcn_exp2f(-1.442695041f * x);
    return __builtin_amdgcn_rcpf(1.f + e);
}
__device__ __forceinline__ float ftanh(float x) {
    x = fmaxf(x, -20.f);
    float e = __builtin_amdgcn_exp2f(-2.885390082f * x);
    return (1.f - e) * __builtin_amdgcn_rcpf(1.f + e);
}

// load 5 f-rows' x data (2 float4 each) for this blk into register buffers
#define LOAD5(F0, XA, XB)                                                     \
    do {                                                                      \
        _Pragma("unroll")                                                     \
        for (int u = 0; u < 5; u++) {                                         \
            const float4* xp =                                                \
                (const float4*)(xs + (fb + (F0) + u) * CHUNK + ib0);          \
            XA[u] = xp[0];                                                    \
            XB[u] = xp[1];                                                    \
        }                                                                     \
    } while (0)

// accumulate 5 f-rows' xg0 partial products from register buffers
#define COMP5(F0, XA, XB)                                                     \
    do {                                                                      \
        _Pragma("unroll")                                                     \
        for (int u = 0; u < 5; u++) {                                         \
            v2f w0 = splat2(cr0[(F0) + u]);                                   \
            v2f w1 = splat2(cr1[(F0) + u]);                                   \
            v2f w2 = splat2(cr2[(F0) + u]);                                   \
            v2f xv0 = mkv2(XA[u].x, XA[u].y);                                 \
            v2f xv1 = mkv2(XA[u].z, XA[u].w);                                 \
            v2f xv2 = mkv2(XB[u].x, XB[u].y);                                 \
            v2f xv3 = mkv2(XB[u].z, XB[u].w);                                 \
            a0[0] = v2fma(w0, xv0, a0[0]); a0[1] = v2fma(w0, xv1, a0[1]);     \
            a0[2] = v2fma(w0, xv2, a0[2]); a0[3] = v2fma(w0, xv3, a0[3]);     \
            a1[0] = v2fma(w1, xv0, a1[0]); a1[1] = v2fma(w1, xv1, a1[1]);     \
            a1[2] = v2fma(w1, xv2, a1[2]); a1[3] = v2fma(w1, xv3, a1[3]);     \
            a2[0] = v2fma(w2, xv0, a2[0]); a2[1] = v2fma(w2, xv1, a2[1]);     \
            a2[2] = v2fma(w2, xv2, a2[2]); a2[3] = v2fma(w2, xv3, a2[3]);     \
        }                                                                     \
    } while (0)

// ---------------------------------------------------------------------------
// One 64-thread (single-wave) block per (batch, expert); unrouted blocks exit.
// Role split with 1-step skew: half0 lane j = L0(t) row j; half1 lane j =
// L1(t-1) row j.  h0 broadcast via v_readlane; h1 via LDS round trip (covered
// by transport + A-dots).  No barriers (single wave).
// Round-5: staging loop software-pipelined (batched global loads).
// Round-6: (a) folded xg0 weights (CT) held in 75 REGISTERS per lane, loaded
// once from global - they were loop-invariant yet re-read from LDS 225x;
// (b) xs partials reads software-pipelined in 5-row groups with ping-pong
// register buffers so LDS latency hides under the FMA stream.
// ---------------------------------------------------------------------------
__global__ __launch_bounds__(64, 1)
void moe_gru_kernel(const float* __restrict__ x,
                    const int*   __restrict__ horizon,
                    const float* __restrict__ emb,
                    const float* __restrict__ W_gate,
                    const float* __restrict__ b_gate,
                    const float* __restrict__ b_in,
                    const float* __restrict__ Wih0,
                    const float* __restrict__ Whh0,
                    const float* __restrict__ bih0,
                    const float* __restrict__ bhh0,
                    const float* __restrict__ Wih1,
                    const float* __restrict__ Whh1,
                    const float* __restrict__ bih1,
                    const float* __restrict__ bhh1,
                    const float* __restrict__ Wh1,
                    const float* __restrict__ bh1,
                    const float* __restrict__ Wh2,
                    const float* __restrict__ bh2,
                    const float* __restrict__ Cg,
                    float* __restrict__ out) {
    __shared__ __align__(16) float smem[3600 + 64 + 64 + 32];
    float* xs  = smem;                  // [f][CHUNK] transposed x chunk
    float* heL = smem + 3600;           // 64: h_embed
    float* bbL = heL + 64;              // 64: b_in + h_embed
    float* h1L = bbL + 64;              // 32: h1 exchange + final h1 for head

    const int bid = blockIdx.x;
    const int b   = bid >> 2;
    const int e   = bid & 3;
    const int tid = threadIdx.x;
    const int j   = tid & 31;
    const int hlf = tid >> 5;
    const int k0h = hlf << 4;
    const int fb  = 25 * hlf;

    // ---- stage h_embed / (b_in + h_embed) (wave-synchronous) ----
    {
        int hor = horizon[b];
        float he = emb[(size_t)hor * ND + tid];
        heL[tid] = he;
        bbL[tid] = he + b_in[tid];
    }

    // ---- gating (every thread computes identically) ----
    float lg[NE];
    #pragma unroll
    for (int q = 0; q < NE; q++) {
        float s = b_gate[q];
        for (int d = 0; d < ND; d++) s += heL[d] * W_gate[q * ND + d];
        lg[q] = s;
    }
    int i1 = 0;
    #pragma unroll
    for (int q = 1; q < NE; q++) if (lg[q] > lg[i1]) i1 = q;
    int i2 = (i1 == 0) ? 1 : 0;
    #pragma unroll
    for (int q = 0; q < NE; q++) if (q != i1 && lg[q] > lg[i2]) i2 = q;
    if (e != i1 && e != i2) return;          // block-uniform
    const float ex2 = expf(lg[i2] - lg[i1]);
    const float wgt = (e == i1) ? (1.f / (1.f + ex2)) : (ex2 / (1.f + ex2));

    // ---- folded xg0 weights -> 75 registers (loop-invariant; was LDS) ----
    float cr0[25], cr1[25], cr2[25];
    {
        const float* cgB = Cg + (size_t)e * NF * G3 + (size_t)fb * G3 + j;
        #pragma unroll
        for (int f = 0; f < 25; f++) {
            cr0[f] = cgB[f * G3];
            cr1[f] = cgB[f * G3 + 32];
            cr2[f] = cgB[f * G3 + 64];
        }
    }

    // ---- per-lane weights ----
    // selA: half0 -> Whh0 rows {j, j+32, j+64}; half1 -> Wih1 rows (full 32-k)
    v2f sA0[16], sA1[16], sA2[16];
    // wB: Whh1 rows {j, j+32, j+64}, k-half [k0h, k0h+16)
    v2f wB0[8], wB1[8], wB2[8];
    {
        const float* baseA = (hlf ? Wih1 : Whh0) + (size_t)e * G3 * NH;
        const float* rA0 = baseA + (size_t)j * NH;
        const float* rA1 = baseA + (size_t)(j + 32) * NH;
        const float* rA2 = baseA + (size_t)(j + 64) * NH;
        #pragma unroll
        for (int q4 = 0; q4 < 8; q4++) {
            float4 qa = ((const float4*)rA0)[q4];
            sA0[2*q4] = mkv2(qa.x, qa.y); sA0[2*q4+1] = mkv2(qa.z, qa.w);
            float4 qb = ((const float4*)rA1)[q4];
            sA1[2*q4] = mkv2(qb.x, qb.y); sA1[2*q4+1] = mkv2(qb.z, qb.w);
            float4 qc = ((const float4*)rA2)[q4];
            sA2[2*q4] = mkv2(qc.x, qc.y); sA2[2*q4+1] = mkv2(qc.z, qc.w);
        }
        const float* baseB = Whh1 + (size_t)e * G3 * NH;
        const float* rB0 = baseB + (size_t)j * NH + k0h;
        const float* rB1 = baseB + (size_t)(j + 32) * NH + k0h;
        const float* rB2 = baseB + (size_t)(j + 64) * NH + k0h;
        #pragma unroll
        for (int q4 = 0; q4 < 4; q4++) {
            float4 qa = ((const float4*)rB0)[q4];
            wB0[2*q4] = mkv2(qa.x, qa.y); wB0[2*q4+1] = mkv2(qa.z, qa.w);
            float4 qb = ((const float4*)rB1)[q4];
            wB1[2*q4] = mkv2(qb.x, qb.y); wB1[2*q4+1] = mkv2(qb.z, qb.w);
            float4 qc = ((const float4*)rB2)[q4];
            wB2[2*q4] = mkv2(qc.x, qc.y); wB2[2*q4+1] = mkv2(qc.z, qc.w);
        }
    }
    const float selb0 = hlf ? bih1[e*G3 + j]      : bhh0[e*G3 + j];
    const float selb1 = hlf ? bih1[e*G3 + j + 32] : bhh0[e*G3 + j + 32];
    const float selb2 = hlf ? bih1[e*G3 + j + 64] : bhh0[e*G3 + j + 64];
    const float whb0  = hlf ? 0.f : bhh1[e*G3 + j];
    const float whb1  = hlf ? 0.f : bhh1[e*G3 + j + 32];
    const float whb2  = hlf ? 0.f : bhh1[e*G3 + j + 64];

    // dreg = bih0 + Wih0 @ (b_in + h_embed), added once (half0 side of reduce)
    float dreg0, dreg1, dreg2;
    {
        float s0 = bih0[e*G3 + j], s1 = bih0[e*G3 + j + 32], s2 = bih0[e*G3 + j + 64];
        const float* w0 = Wih0 + ((size_t)e * G3 + j) * ND;
        const float* w1 = Wih0 + ((size_t)e * G3 + j + 32) * ND;
        const float* w2 = Wih0 + ((size_t)e * G3 + j + 64) * ND;
        for (int d = 0; d < ND; d++) {
            float bb = bbL[d];
            s0 += w0[d] * bb; s1 += w1[d] * bb; s2 += w2[d] * bb;
        }
        dreg0 = hlf ? 0.f : s0;
        dreg1 = hlf ? 0.f : s1;
        dreg2 = hlf ? 0.f : s2;
    }

    // ---- pipeline state ----
    v2f h0v[16], h1v[8];
    #pragma unroll
    for (int k = 0; k < 16; k++) h0v[k] = splat2(0.f);
    #pragma unroll
    for (int k = 0; k < 8; k++)  h1v[k] = splat2(0.f);
    float hold = 0.f;                    // half0: h0_j ; half1: h1_j (skewed)
    float lmul = hlf ? 0.f : 1.f;        // neutralizes the fake first L1 step
    if (tid < 32) h1L[tid] = 0.f;

    const float* xg = x + (size_t)b * LSEQ * NF;

    for (int ch = 0; ch < NCHUNK; ch++) {
        // ---- stage x chunk: software-pipelined (batched loads, then
        // transpose-writes).  (CHUNK*NF)/4 = 900 float4s; u=0..13 covers
        // i4 = tid + 64u <= 895, remainder 896..899 handled by tid < 4. ----
        {
            const float4* xc4 = (const float4*)(xg + (size_t)ch * CHUNK * NF);
            float4 vb[7];
            // batch 1: issue 7 loads, then write
            #pragma unroll
            for (int u = 0; u < 7; u++) vb[u] = xc4[tid + 64 * u];
            #pragma unroll
            for (int u = 0; u < 7; u++) {
                int idx = (tid + 64 * u) * 4;
                #pragma unroll
                for (int uu = 0; uu < 4; uu++) {
                    int id = idx + uu;
                    int it = (int)(((unsigned)id * 5243u) >> 18);   // id/50
                    int f  = id - it * 50;
                    float val = (uu == 0) ? vb[u].x : (uu == 1) ? vb[u].y
                              : (uu == 2) ? vb[u].z : vb[u].w;
                    xs[f * CHUNK + it] = val;
                }
            }
            // batch 2: issue 7 loads, then write
            #pragma unroll
            for (int u = 0; u < 7; u++) vb[u] = xc4[tid + 64 * (u + 7)];
            #pragma unroll
            for (int u = 0; u < 7; u++) {
                int idx = (tid + 64 * (u + 7)) * 4;
                #pragma unroll
                for (int uu = 0; uu < 4; uu++) {
                    int id = idx + uu;
                    int it = (int)(((unsigned)id * 5243u) >> 18);   // id/50
                    int f  = id - it * 50;
                    float val = (uu == 0) ? vb[u].x : (uu == 1) ? vb[u].y
                              : (uu == 2) ? vb[u].z : vb[u].w;
                    xs[f * CHUNK + it] = val;
                }
            }
            // remainder: i4 = 896..899
            if (tid < 4) {
                float4 v = xc4[896 + tid];
                int idx = (896 + tid) * 4;
                #pragma unroll
                for (int uu = 0; uu < 4; uu++) {
                    int id = idx + uu;
                    int it = (int)(((unsigned)id * 5243u) >> 18);   // id/50
                    int f  = id - it * 50;
                    float val = (uu == 0) ? v.x : (uu == 1) ? v.y
                              : (uu == 2) ? v.z : v.w;
                    xs[f * CHUNK + it] = val;
                }
            }
        }

        for (int blk = 0; blk < NBLK; blk++) {
            const int ib0 = blk * TBLK;
            // ---- xg0 partials for TBLK steps (f-split across halves),
            // software-pipelined in 5-row groups (ping-pong reg buffers) ----
            v2f a0[4], a1[4], a2[4];
            #pragma unroll
            for (int p = 0; p < 4; p++) {
                a0[p] = splat2(dreg0); a1[p] = splat2(dreg1); a2[p] = splat2(dreg2);
            }
            {
                float4 qa[5], qb[5], ra[5], rb[5];
                LOAD5(0, qa, qb);
                LOAD5(5, ra, rb);
                COMP5(0, qa, qb);
                LOAD5(10, qa, qb);
                COMP5(5, ra, rb);
                LOAD5(15, ra, rb);
                COMP5(10, qa, qb);
                LOAD5(20, qa, qb);
                COMP5(15, ra, rb);
                COMP5(20, qa, qb);
            }
            // cross-half reduce of xg0 (off the per-step chain)
            #pragma unroll
            for (int p = 0; p < 4; p++) {
                a0[p].x += __shfl_xor(a0[p].x, 32, 64); a0[p].y += __shfl_xor(a0[p].y, 32, 64);
                a1[p].x += __shfl_xor(a1[p].x, 32, 64); a1[p].y += __shfl_xor(a1[p].y, 32, 64);
                a2[p].x += __shfl_xor(a2[p].x, 32, 64); a2[p].y += __shfl_xor(a2[p].y, 32, 64);
            }

            // ---- TBLK pipelined steps: L0(t) on half0 || L1(t-1) on half1 ----
            #pragma unroll
            for (int i = 0; i < TBLK; i++) {
                // B-dots (k-half over h1 from LDS), start the xor32 reduce
                v2f dB0 = mkv2(whb0, 0.f), dB1 = mkv2(whb1, 0.f), dB2 = mkv2(whb2, 0.f);
                #pragma unroll
                for (int k = 0; k < 8; k++) {
                    dB0 = v2fma(wB0[k], h1v[k], dB0);
                    dB1 = v2fma(wB1[k], h1v[k], dB1);
                    dB2 = v2fma(wB2[k], h1v[k], dB2);
                }
                float B0 = dB0.x + dB0.y, B1 = dB1.x + dB1.y, B2 = dB2.x + dB2.y;
                float R0 = B0 + __shfl_xor(B0, 32, 64);   // covered by A-dots
                float R1 = B1 + __shfl_xor(B1, 32, 64);
                float R2 = B2 + __shfl_xor(B2, 32, 64);
                // A-dots: full dots over transported h0
                v2f dA0 = mkv2(selb0, 0.f), dA1 = mkv2(selb1, 0.f), dA2 = mkv2(selb2, 0.f);
                #pragma unroll
                for (int k = 0; k < 16; k++) {
                    dA0 = v2fma(sA0[k], h0v[k], dA0);
                    dA1 = v2fma(sA1[k], h0v[k], dA1);
                    dA2 = v2fma(sA2[k], h0v[k], dA2);
                }
                float A0 = dA0.x + dA0.y, A1 = dA1.x + dA1.y, A2 = dA2.x + dA2.y;
                const float ac0 = a0[i >> 1][i & 1];
                const float ac1 = a1[i >> 1][i & 1];
                const float ac2 = a2[i >> 1][i & 1];
                // gate assembly (uniform instructions, per-half operand select)
                float o0   = hlf ? R0 : ac0;
                float o1   = hlf ? R1 : ac1;
                float npre = hlf ? A2 : ac2;
                float gn   = hlf ? R2 : A2;
                float r = fsig(A0 + o0);
                float z = fsig(A1 + o1);
                float n = ftanh(npre + r * gn);
                float hnew = (n + z * (hold - n)) * lmul;
                hold = hnew;
                lmul = 1.f;
                // h1 exchange via LDS (round trip covered by transport + A-dots)
                if (hlf) h1L[j] = hnew;
                const float4* h1q = (const float4*)(h1L + k0h);
                float4 q0 = h1q[0], q1 = h1q[1], q2 = h1q[2], q3 = h1q[3];
                h1v[0] = mkv2(q0.x, q0.y); h1v[1] = mkv2(q0.z, q0.w);
                h1v[2] = mkv2(q1.x, q1.y); h1v[3] = mkv2(q1.z, q1.w);
                h1v[4] = mkv2(q2.x, q2.y); h1v[5] = mkv2(q2.z, q2.w);
                h1v[6] = mkv2(q3.x, q3.y); h1v[7] = mkv2(q3.z, q3.w);
                // h0 broadcast via v_readlane: VALU-only, no DS latency
                {
                    int hni = __float_as_int(hnew);
                    #pragma unroll
                    for (int k = 0; k < 16; k++) {
                        float e0 = __int_as_float(__builtin_amdgcn_readlane(hni, 2*k));
                        float e1 = __int_as_float(__builtin_amdgcn_readlane(hni, 2*k+1));
                        h0v[k] = mkv2(e0, e1);
                    }
                }
            }
        }
    }

    // ---- epilogue: L1(LSEQ-1) (results used from half1 only) ----
    {
        v2f dA0 = mkv2(selb0, 0.f), dA1 = mkv2(selb1, 0.f), dA2 = mkv2(selb2, 0.f);
        #pragma unroll
        for (int k = 0; k < 16; k++) {
            dA0 = v2fma(sA0[k], h0v[k], dA0);
            dA1 = v2fma(sA1[k], h0v[k], dA1);
            dA2 = v2fma(sA2[k], h0v[k], dA2);
        }
        v2f dB0 = mkv2(whb0, 0.f), dB1 = mkv2(whb1, 0.f), dB2 = mkv2(whb2, 0.f);
        #pragma unroll
        for (int k = 0; k < 8; k++) {
            dB0 = v2fma(wB0[k], h1v[k], dB0);
            dB1 = v2fma(wB1[k], h1v[k], dB1);
            dB2 = v2fma(wB2[k], h1v[k], dB2);
        }
        float A0 = dA0.x + dA0.y, A1 = dA1.x + dA1.y, A2 = dA2.x + dA2.y;
        float B0 = dB0.x + dB0.y, B1 = dB1.x + dB1.y, B2 = dB2.x + dB2.y;
        float R0 = B0 + __shfl_xor(B0, 32, 64);
        float R1 = B1 + __shfl_xor(B1, 32, 64);
        float R2 = B2 + __shfl_xor(B2, 32, 64);
        float r = fsig(A0 + R0);
        float z = fsig(A1 + R1);
        float n = ftanh(A2 + r * R2);
        float hfin = n + z * (hold - n);
        if (hlf) h1L[j] = hfin;
    }

    // ---- head MLP + weighted accumulation ----
    if (tid < 32) {
        float s = bh1[e * NHU + tid];
        const float* wr = Wh1 + ((size_t)e * NHU + tid) * NH;
        #pragma unroll
        for (int d = 0; d < NH; d++) s += wr[d] * h1L[d];
        float hid = fmaxf(s, 0.f);
        float c = hid * Wh2[e * NHU + tid];
        #pragma unroll
        for (int off = 16; off > 0; off >>= 1) c += __shfl_down(c, off, 64);
        if (tid == 0) atomicAdd(out + b, wgt * (c + bh2[e]));
    }
}

extern "C" void kernel_launch(void* const* d_in, const int* in_sizes, int n_in,
                              void* d_out, int out_size, void* d_ws, size_t ws_size,
                              hipStream_t stream) {
    const float* x       = (const float*)d_in[0];
    const int*   horizon = (const int*)  d_in[1];
    const float* W_in    = (const float*)d_in[2];
    const float* b_in    = (const float*)d_in[3];
    const float* emb     = (const float*)d_in[4];
    const float* W_gate  = (const float*)d_in[5];
    const float* b_gate  = (const float*)d_in[6];
    const float* Wih0    = (const float*)d_in[7];
    const float* Whh0    = (const float*)d_in[8];
    const float* bih0    = (const float*)d_in[9];
    const float* bhh0    = (const float*)d_in[10];
    const float* Wih1    = (const float*)d_in[11];
    const float* Whh1    = (const float*)d_in[12];
    const float* bih1    = (const float*)d_in[13];
    const float* bhh1    = (const float*)d_in[14];
    const float* Wh1     = (const float*)d_in[15];
    const float* bh1     = (const float*)d_in[16];
    const float* Wh2     = (const float*)d_in[17];
    const float* bh2     = (const float*)d_in[18];
    float* out = (float*)d_out;
    float* Cg  = (float*)d_ws;   // NE*NF*G3 floats = 76.8 KB

    hipMemsetAsync(d_out, 0, NB * sizeof(float), stream);
    compute_C_kernel<<<dim3(NE), dim3(256), 0, stream>>>(Wih0, W_in, Cg);
    moe_gru_kernel<<<dim3(NB * NE), dim3(64), 0, stream>>>(
        x, horizon, emb, W_gate, b_gate, b_in,
        Wih0, Whh0, bih0, bhh0, Wih1, Whh1, bih1, bhh1,
        Wh1, bh1, Wh2, bh2, Cg, out);
}

// Round 7
// 1352.357 us; speedup vs baseline: 1.0012x; 1.0012x over previous
//
#include <hip/hip_runtime.h>
#include <math.h>

#define NB   256
#define LSEQ 1800
#define NF   50
#define NE   4
#define NH   32
#define G3   96
#define ND   64
#define NHU  32
#define CHUNK 72
#define TBLK  8
#define NCHUNK (LSEQ / CHUNK)   // 25
#define NBLK   (CHUNK / TBLK)   // 9

typedef float v2f __attribute__((ext_vector_type(2)));

// Packed fp32 FMA (VOP3P).  d.lo = a.lo*b.lo + c.lo ; d.hi = a.hi*b.hi + c.hi
// -- the compiler lowers __builtin_elementwise_fma(v2f) to TWO v_fma_f32
// (round-6 counter math: ~420 issued instr/step vs ~200 source v2f ops), so
// force the single packed instruction.  Bitwise-identical results.
__device__ __forceinline__ v2f v2fma(v2f a, v2f b, v2f c) {
    asm("v_pk_fma_f32 %0, %1, %2, %0" : "+v"(c) : "v"(a), "v"(b));
    return c;
}
__device__ __forceinline__ v2f mkv2(float a, float b) { v2f t; t.x = a; t.y = b; return t; }
__device__ __forceinline__ v2f splat2(float s) { v2f t; t.x = s; t.y = s; return t; }

// ---------------------------------------------------------------------------
// Kernel 1: fold input projection into layer-0 input weights.
// Cg[e][f][g] = sum_d Wih0[e][g][d] * W_in[d][f]   (scalar [f][96] layout:
// b32 reads at bank j -> conflict-free)
// ---------------------------------------------------------------------------
__global__ void compute_C_kernel(const float* __restrict__ Wih0,
                                 const float* __restrict__ W_in,
                                 float* __restrict__ Cg) {
    int e = blockIdx.x;
    for (int idx = threadIdx.x; idx < NF * G3; idx += blockDim.x) {
        int f = idx / G3;
        int g = idx - f * G3;
        const float* wr = Wih0 + ((size_t)e * G3 + g) * ND;
        float s = 0.f;
        #pragma unroll 8
        for (int d = 0; d < ND; d++) s += wr[d] * W_in[d * NF + f];
        Cg[(size_t)e * NF * G3 + idx] = s;
    }
}

// Fast transcendentals on v_exp_f32 / v_rcp_f32.
__device__ __forceinline__ float fsig(float x) {
    float e = __builtin_amdgcn_exp2f(-1.442695041f * x);
    return __builtin_amdgcn_rcpf(1.f + e);
}
__device__ __forceinline__ float ftanh(float x) {
    x = fmaxf(x, -20.f);
    float e = __builtin_amdgcn_exp2f(-2.885390082f * x);
    return (1.f - e) * __builtin_amdgcn_rcpf(1.f + e);
}

// ---------------------------------------------------------------------------
// One 64-thread (single-wave) block per (batch, expert); unrouted blocks exit.
// Role split with 1-step skew: half0 lane j = L0(t) row j (full 32-dots over
// h0); half1 lane j = L1(t-1) row j (xg1 full dots over h0 + gh1 k-half dots
// over h1, one xor32 reduce). h0 broadcast via v_readlane (VALU-only, no DS
// latency); h1 exchanged through LDS with its round trip covered by the
// transport + A-dots. No barriers (single wave).
// Round-5: staging loop software-pipelined (batched global loads).
// Round-7: all dot-product FMAs forced to v_pk_fma_f32 (packed fp32).
// ---------------------------------------------------------------------------
__global__ __launch_bounds__(64, 1)
void moe_gru_kernel(const float* __restrict__ x,
                    const int*   __restrict__ horizon,
                    const float* __restrict__ emb,
                    const float* __restrict__ W_gate,
                    const float* __restrict__ b_gate,
                    const float* __restrict__ b_in,
                    const float* __restrict__ Wih0,
                    const float* __restrict__ Whh0,
                    const float* __restrict__ bih0,
                    const float* __restrict__ bhh0,
                    const float* __restrict__ Wih1,
                    const float* __restrict__ Whh1,
                    const float* __restrict__ bih1,
                    const float* __restrict__ bhh1,
                    const float* __restrict__ Wh1,
                    const float* __restrict__ bh1,
                    const float* __restrict__ Wh2,
                    const float* __restrict__ bh2,
                    const float* __restrict__ Cg,
                    float* __restrict__ out) {
    __shared__ __align__(16) float smem[4800 + 3600 + 64 + 64 + 32];
    float* CT  = smem;                  // [f][96] folded xg0 weights
    float* xs  = smem + 4800;           // [f][CHUNK] transposed x chunk
    float* heL = smem + 4800 + 3600;    // 64: h_embed
    float* bbL = heL + 64;              // 64: b_in + h_embed
    float* h1L = bbL + 64;              // 32: h1 exchange + final h1 for head

    const int bid = blockIdx.x;
    const int b   = bid >> 2;
    const int e   = bid & 3;
    const int tid = threadIdx.x;
    const int j   = tid & 31;
    const int hlf = tid >> 5;
    const int k0h = hlf << 4;

    // ---- stage h_embed / (b_in + h_embed) (wave-synchronous) ----
    {
        int hor = horizon[b];
        float he = emb[(size_t)hor * ND + tid];
        heL[tid] = he;
        bbL[tid] = he + b_in[tid];
    }

    // ---- gating (every thread computes identically) ----
    float lg[NE];
    #pragma unroll
    for (int q = 0; q < NE; q++) {
        float s = b_gate[q];
        for (int d = 0; d < ND; d++) s += heL[d] * W_gate[q * ND + d];
        lg[q] = s;
    }
    int i1 = 0;
    #pragma unroll
    for (int q = 1; q < NE; q++) if (lg[q] > lg[i1]) i1 = q;
    int i2 = (i1 == 0) ? 1 : 0;
    #pragma unroll
    for (int q = 0; q < NE; q++) if (q != i1 && lg[q] > lg[i2]) i2 = q;
    if (e != i1 && e != i2) return;          // block-uniform
    const float ex2 = expf(lg[i2] - lg[i1]);
    const float wgt = (e == i1) ? (1.f / (1.f + ex2)) : (ex2 / (1.f + ex2));

    // ---- stage folded xg0 weights into LDS ----
    for (int idx = tid; idx < NF * G3; idx += 64)
        CT[idx] = Cg[(size_t)e * NF * G3 + idx];

    // ---- per-lane weights ----
    // selA: half0 -> Whh0 rows {j, j+32, j+64}; half1 -> Wih1 rows (full 32-k)
    v2f sA0[16], sA1[16], sA2[16];
    // wB: Whh1 rows {j, j+32, j+64}, k-half [k0h, k0h+16)
    v2f wB0[8], wB1[8], wB2[8];
    {
        const float* baseA = (hlf ? Wih1 : Whh0) + (size_t)e * G3 * NH;
        const float* rA0 = baseA + (size_t)j * NH;
        const float* rA1 = baseA + (size_t)(j + 32) * NH;
        const float* rA2 = baseA + (size_t)(j + 64) * NH;
        #pragma unroll
        for (int q4 = 0; q4 < 8; q4++) {
            float4 qa = ((const float4*)rA0)[q4];
            sA0[2*q4] = mkv2(qa.x, qa.y); sA0[2*q4+1] = mkv2(qa.z, qa.w);
            float4 qb = ((const float4*)rA1)[q4];
            sA1[2*q4] = mkv2(qb.x, qb.y); sA1[2*q4+1] = mkv2(qb.z, qb.w);
            float4 qc = ((const float4*)rA2)[q4];
            sA2[2*q4] = mkv2(qc.x, qc.y); sA2[2*q4+1] = mkv2(qc.z, qc.w);
        }
        const float* baseB = Whh1 + (size_t)e * G3 * NH;
        const float* rB0 = baseB + (size_t)j * NH + k0h;
        const float* rB1 = baseB + (size_t)(j + 32) * NH + k0h;
        const float* rB2 = baseB + (size_t)(j + 64) * NH + k0h;
        #pragma unroll
        for (int q4 = 0; q4 < 4; q4++) {
            float4 qa = ((const float4*)rB0)[q4];
            wB0[2*q4] = mkv2(qa.x, qa.y); wB0[2*q4+1] = mkv2(qa.z, qa.w);
            float4 qb = ((const float4*)rB1)[q4];
            wB1[2*q4] = mkv2(qb.x, qb.y); wB1[2*q4+1] = mkv2(qb.z, qb.w);
            float4 qc = ((const float4*)rB2)[q4];
            wB2[2*q4] = mkv2(qc.x, qc.y); wB2[2*q4+1] = mkv2(qc.z, qc.w);
        }
    }
    const float selb0 = hlf ? bih1[e*G3 + j]      : bhh0[e*G3 + j];
    const float selb1 = hlf ? bih1[e*G3 + j + 32] : bhh0[e*G3 + j + 32];
    const float selb2 = hlf ? bih1[e*G3 + j + 64] : bhh0[e*G3 + j + 64];
    const float whb0  = hlf ? 0.f : bhh1[e*G3 + j];
    const float whb1  = hlf ? 0.f : bhh1[e*G3 + j + 32];
    const float whb2  = hlf ? 0.f : bhh1[e*G3 + j + 64];

    // dreg = bih0 + Wih0 @ (b_in + h_embed), added once (half0 side of reduce)
    float dreg0, dreg1, dreg2;
    {
        float s0 = bih0[e*G3 + j], s1 = bih0[e*G3 + j + 32], s2 = bih0[e*G3 + j + 64];
        const float* w0 = Wih0 + ((size_t)e * G3 + j) * ND;
        const float* w1 = Wih0 + ((size_t)e * G3 + j + 32) * ND;
        const float* w2 = Wih0 + ((size_t)e * G3 + j + 64) * ND;
        for (int d = 0; d < ND; d++) {
            float bb = bbL[d];
            s0 += w0[d] * bb; s1 += w1[d] * bb; s2 += w2[d] * bb;
        }
        dreg0 = hlf ? 0.f : s0;
        dreg1 = hlf ? 0.f : s1;
        dreg2 = hlf ? 0.f : s2;
    }

    // ---- pipeline state ----
    v2f h0v[16], h1v[8];
    #pragma unroll
    for (int k = 0; k < 16; k++) h0v[k] = splat2(0.f);
    #pragma unroll
    for (int k = 0; k < 8; k++)  h1v[k] = splat2(0.f);
    float hold = 0.f;                    // half0: h0_j ; half1: h1_j (skewed)
    float lmul = hlf ? 0.f : 1.f;        // neutralizes the fake first L1 step
    if (tid < 32) h1L[tid] = 0.f;

    const float* xg = x + (size_t)b * LSEQ * NF;

    for (int ch = 0; ch < NCHUNK; ch++) {
        // ---- stage x chunk: software-pipelined (batched loads, then
        // transpose-writes).  (CHUNK*NF)/4 = 900 float4s; u=0..13 covers
        // i4 = tid + 64u <= 895, remainder 896..899 handled by tid < 4. ----
        {
            const float4* xc4 = (const float4*)(xg + (size_t)ch * CHUNK * NF);
            float4 vb[7];
            // batch 1: issue 7 loads, then write
            #pragma unroll
            for (int u = 0; u < 7; u++) vb[u] = xc4[tid + 64 * u];
            #pragma unroll
            for (int u = 0; u < 7; u++) {
                int idx = (tid + 64 * u) * 4;
                #pragma unroll
                for (int uu = 0; uu < 4; uu++) {
                    int id = idx + uu;
                    int it = (int)(((unsigned)id * 5243u) >> 18);   // id/50
                    int f  = id - it * 50;
                    float val = (uu == 0) ? vb[u].x : (uu == 1) ? vb[u].y
                              : (uu == 2) ? vb[u].z : vb[u].w;
                    xs[f * CHUNK + it] = val;
                }
            }
            // batch 2: issue 7 loads, then write
            #pragma unroll
            for (int u = 0; u < 7; u++) vb[u] = xc4[tid + 64 * (u + 7)];
            #pragma unroll
            for (int u = 0; u < 7; u++) {
                int idx = (tid + 64 * (u + 7)) * 4;
                #pragma unroll
                for (int uu = 0; uu < 4; uu++) {
                    int id = idx + uu;
                    int it = (int)(((unsigned)id * 5243u) >> 18);   // id/50
                    int f  = id - it * 50;
                    float val = (uu == 0) ? vb[u].x : (uu == 1) ? vb[u].y
                              : (uu == 2) ? vb[u].z : vb[u].w;
                    xs[f * CHUNK + it] = val;
                }
            }
            // remainder: i4 = 896..899
            if (tid < 4) {
                float4 v = xc4[896 + tid];
                int idx = (896 + tid) * 4;
                #pragma unroll
                for (int uu = 0; uu < 4; uu++) {
                    int id = idx + uu;
                    int it = (int)(((unsigned)id * 5243u) >> 18);   // id/50
                    int f  = id - it * 50;
                    float val = (uu == 0) ? v.x : (uu == 1) ? v.y
                              : (uu == 2) ? v.z : v.w;
                    xs[f * CHUNK + it] = val;
                }
            }
        }

        for (int blk = 0; blk < NBLK; blk++) {
            const int ib0 = blk * TBLK;
            // ---- xg0 partials for TBLK steps (f-split across halves) ----
            v2f a0[4], a1[4], a2[4];
            #pragma unroll
            for (int p = 0; p < 4; p++) {
                a0[p] = splat2(dreg0); a1[p] = splat2(dreg1); a2[p] = splat2(dreg2);
            }
            {
                const int fb = 25 * hlf;
                #pragma unroll 5
                for (int f = 0; f < 25; f++) {
                    const int fg = fb + f;
                    float c0 = CT[fg * G3 + j];
                    float c1 = CT[fg * G3 + j + 32];
                    float c2 = CT[fg * G3 + j + 64];
                    const float4* xp = (const float4*)(xs + fg * CHUNK + ib0);
                    float4 xa = xp[0], xb = xp[1];
                    v2f xv[4] = { mkv2(xa.x, xa.y), mkv2(xa.z, xa.w),
                                  mkv2(xb.x, xb.y), mkv2(xb.z, xb.w) };
                    v2f w0 = splat2(c0), w1 = splat2(c1), w2 = splat2(c2);
                    #pragma unroll
                    for (int p = 0; p < 4; p++) {
                        a0[p] = v2fma(w0, xv[p], a0[p]);
                        a1[p] = v2fma(w1, xv[p], a1[p]);
                        a2[p] = v2fma(w2, xv[p], a2[p]);
                    }
                }
            }
            // cross-half reduce of xg0 (off the per-step chain)
            #pragma unroll
            for (int p = 0; p < 4; p++) {
                a0[p].x += __shfl_xor(a0[p].x, 32, 64); a0[p].y += __shfl_xor(a0[p].y, 32, 64);
                a1[p].x += __shfl_xor(a1[p].x, 32, 64); a1[p].y += __shfl_xor(a1[p].y, 32, 64);
                a2[p].x += __shfl_xor(a2[p].x, 32, 64); a2[p].y += __shfl_xor(a2[p].y, 32, 64);
            }

            // ---- TBLK pipelined steps: L0(t) on half0 || L1(t-1) on half1 ----
            #pragma unroll
            for (int i = 0; i < TBLK; i++) {
                // B-dots (k-half over h1 from LDS), start the xor32 reduce
                v2f dB0 = mkv2(whb0, 0.f), dB1 = mkv2(whb1, 0.f), dB2 = mkv2(whb2, 0.f);
                #pragma unroll
                for (int k = 0; k < 8; k++) {
                    dB0 = v2fma(wB0[k], h1v[k], dB0);
                    dB1 = v2fma(wB1[k], h1v[k], dB1);
                    dB2 = v2fma(wB2[k], h1v[k], dB2);
                }
                float B0 = dB0.x + dB0.y, B1 = dB1.x + dB1.y, B2 = dB2.x + dB2.y;
                float R0 = B0 + __shfl_xor(B0, 32, 64);   // covered by A-dots
                float R1 = B1 + __shfl_xor(B1, 32, 64);
                float R2 = B2 + __shfl_xor(B2, 32, 64);
                // A-dots: full dots over transported h0
                v2f dA0 = mkv2(selb0, 0.f), dA1 = mkv2(selb1, 0.f), dA2 = mkv2(selb2, 0.f);
                #pragma unroll
                for (int k = 0; k < 16; k++) {
                    dA0 = v2fma(sA0[k], h0v[k], dA0);
                    dA1 = v2fma(sA1[k], h0v[k], dA1);
                    dA2 = v2fma(sA2[k], h0v[k], dA2);
                }
                float A0 = dA0.x + dA0.y, A1 = dA1.x + dA1.y, A2 = dA2.x + dA2.y;
                const float ac0 = a0[i >> 1][i & 1];
                const float ac1 = a1[i >> 1][i & 1];
                const float ac2 = a2[i >> 1][i & 1];
                // gate assembly (uniform instructions, per-half operand select)
                float o0   = hlf ? R0 : ac0;
                float o1   = hlf ? R1 : ac1;
                float npre = hlf ? A2 : ac2;
                float gn   = hlf ? R2 : A2;
                float r = fsig(A0 + o0);
                float z = fsig(A1 + o1);
                float n = ftanh(npre + r * gn);
                float hnew = (n + z * (hold - n)) * lmul;
                hold = hnew;
                lmul = 1.f;
                // h1 exchange via LDS (round trip covered by transport + A-dots)
                if (hlf) h1L[j] = hnew;
                const float4* h1q = (const float4*)(h1L + k0h);
                float4 q0 = h1q[0], q1 = h1q[1], q2 = h1q[2], q3 = h1q[3];
                h1v[0] = mkv2(q0.x, q0.y); h1v[1] = mkv2(q0.z, q0.w);
                h1v[2] = mkv2(q1.x, q1.y); h1v[3] = mkv2(q1.z, q1.w);
                h1v[4] = mkv2(q2.x, q2.y); h1v[5] = mkv2(q2.z, q2.w);
                h1v[6] = mkv2(q3.x, q3.y); h1v[7] = mkv2(q3.z, q3.w);
                // h0 broadcast via v_readlane: VALU-only, no DS latency
                {
                    int hni = __float_as_int(hnew);
                    #pragma unroll
                    for (int k = 0; k < 16; k++) {
                        float e0 = __int_as_float(__builtin_amdgcn_readlane(hni, 2*k));
                        float e1 = __int_as_float(__builtin_amdgcn_readlane(hni, 2*k+1));
                        h0v[k] = mkv2(e0, e1);
                    }
                }
            }
        }
    }

    // ---- epilogue: L1(LSEQ-1) (results used from half1 only) ----
    {
        v2f dA0 = mkv2(selb0, 0.f), dA1 = mkv2(selb1, 0.f), dA2 = mkv2(selb2, 0.f);
        #pragma unroll
        for (int k = 0; k < 16; k++) {
            dA0 = v2fma(sA0[k], h0v[k], dA0);
            dA1 = v2fma(sA1[k], h0v[k], dA1);
            dA2 = v2fma(sA2[k], h0v[k], dA2);
        }
        v2f dB0 = mkv2(whb0, 0.f), dB1 = mkv2(whb1, 0.f), dB2 = mkv2(whb2, 0.f);
        #pragma unroll
        for (int k = 0; k < 8; k++) {
            dB0 = v2fma(wB0[k], h1v[k], dB0);
            dB1 = v2fma(wB1[k], h1v[k], dB1);
            dB2 = v2fma(wB2[k], h1v[k], dB2);
        }
        float A0 = dA0.x + dA0.y, A1 = dA1.x + dA1.y, A2 = dA2.x + dA2.y;
        float B0 = dB0.x + dB0.y, B1 = dB1.x + dB1.y, B2 = dB2.x + dB2.y;
        float R0 = B0 + __shfl_xor(B0, 32, 64);
        float R1 = B1 + __shfl_xor(B1, 32, 64);
        float R2 = B2 + __shfl_xor(B2, 32, 64);
        float r = fsig(A0 + R0);
        float z = fsig(A1 + R1);
        float n = ftanh(A2 + r * R2);
        float hfin = n + z * (hold - n);
        if (hlf) h1L[j] = hfin;
    }

    // ---- head MLP + weighted accumulation ----
    if (tid < 32) {
        float s = bh1[e * NHU + tid];
        const float* wr = Wh1 + ((size_t)e * NHU + tid) * NH;
        #pragma unroll
        for (int d = 0; d < NH; d++) s += wr[d] * h1L[d];
        float hid = fmaxf(s, 0.f);
        float c = hid * Wh2[e * NHU + tid];
        #pragma unroll
        for (int off = 16; off > 0; off >>= 1) c += __shfl_down(c, off, 64);
        if (tid == 0) atomicAdd(out + b, wgt * (c + bh2[e]));
    }
}

extern "C" void kernel_launch(void* const* d_in, const int* in_sizes, int n_in,
                              void* d_out, int out_size, void* d_ws, size_t ws_size,
                              hipStream_t stream) {
    const float* x       = (const float*)d_in[0];
    const int*   horizon = (const int*)  d_in[1];
    const float* W_in    = (const float*)d_in[2];
    const float* b_in    = (const float*)d_in[3];
    const float* emb     = (const float*)d_in[4];
    const float* W_gate  = (const float*)d_in[5];
    const float* b_gate  = (const float*)d_in[6];
    const float* Wih0    = (const float*)d_in[7];
    const float* Whh0    = (const float*)d_in[8];
    const float* bih0    = (const float*)d_in[9];
    const float* bhh0    = (const float*)d_in[10];
    const float* Wih1    = (const float*)d_in[11];
    const float* Whh1    = (const float*)d_in[12];
    const float* bih1    = (const float*)d_in[13];
    const float* bhh1    = (const float*)d_in[14];
    const float* Wh1     = (const float*)d_in[15];
    const float* bh1     = (const float*)d_in[16];
    const float* Wh2     = (const float*)d_in[17];
    const float* bh2     = (const float*)d_in[18];
    float* out = (float*)d_out;
    float* Cg  = (float*)d_ws;   // NE*NF*G3 floats = 76.8 KB

    hipMemsetAsync(d_out, 0, NB * sizeof(float), stream);
    compute_C_kernel<<<dim3(NE), dim3(256), 0, stream>>>(Wih0, W_in, Cg);
    moe_gru_kernel<<<dim3(NB * NE), dim3(64), 0, stream>>>(
        x, horizon, emb, W_gate, b_gate, b_in,
        Wih0, Whh0, bih0, bhh0, Wih1, Whh1, bih1, bhh1,
        Wh1, bh1, Wh2, bh2, Cg, out);
}

// Round 8
// 1221.533 us; speedup vs baseline: 1.1085x; 1.1071x over previous
//
#include <hip/hip_runtime.h>
#include <math.h>

#define NB   256
#define LSEQ 1800
#define NF   50
#define NE   4
#define NH   32
#define G3   96
#define ND   64
#define NHU  32
#define CHUNK 72
#define TBLK  8
#define NCHUNK (LSEQ / CHUNK)   // 25
#define NBLK   (CHUNK / TBLK)   // 9

typedef float v2f __attribute__((ext_vector_type(2)));

__device__ __forceinline__ v2f v2fma(v2f a, v2f b, v2f c) {
    return __builtin_elementwise_fma(a, b, c);
}
__device__ __forceinline__ v2f mkv2(float a, float b) { v2f t; t.x = a; t.y = b; return t; }
__device__ __forceinline__ v2f splat2(float s) { v2f t; t.x = s; t.y = s; return t; }

// xor-32 sum across wave halves via v_permlane32_swap_b32 (VALU, ~4cy) --
// replaces ds_bpermute (~120cy DS latency + in-order lgkm queue drain).
// After swap(t,u) with t=u=v: t[i] = v[i^32], u[i] = v[i]  ->  t+u is the
// cross-half sum in EVERY lane (fp add commutative: bitwise == B + shfl).
__device__ __forceinline__ float xor32sum(float v) {
    float t = v, u = v;
    asm("v_permlane32_swap_b32 %0, %1" : "+v"(t), "+v"(u));
    return t + u;
}

// ---------------------------------------------------------------------------
// Kernel 1: fold input projection into layer-0 input weights.
// Cg[e][f][g] = sum_d Wih0[e][g][d] * W_in[d][f]   (scalar [f][96] layout:
// b32 reads at bank j -> conflict-free)
// ---------------------------------------------------------------------------
__global__ void compute_C_kernel(const float* __restrict__ Wih0,
                                 const float* __restrict__ W_in,
                                 float* __restrict__ Cg) {
    int e = blockIdx.x;
    for (int idx = threadIdx.x; idx < NF * G3; idx += blockDim.x) {
        int f = idx / G3;
        int g = idx - f * G3;
        const float* wr = Wih0 + ((size_t)e * G3 + g) * ND;
        float s = 0.f;
        #pragma unroll 8
        for (int d = 0; d < ND; d++) s += wr[d] * W_in[d * NF + f];
        Cg[(size_t)e * NF * G3 + idx] = s;
    }
}

// Fast transcendentals on v_exp_f32 / v_rcp_f32.
__device__ __forceinline__ float fsig(float x) {
    float e = __builtin_amdgcn_exp2f(-1.442695041f * x);
    return __builtin_amdgcn_rcpf(1.f + e);
}
__device__ __forceinline__ float ftanh(float x) {
    x = fmaxf(x, -20.f);
    float e = __builtin_amdgcn_exp2f(-2.885390082f * x);
    return (1.f - e) * __builtin_amdgcn_rcpf(1.f + e);
}

// ---------------------------------------------------------------------------
// One 64-thread (single-wave) block per (batch, expert); unrouted blocks exit.
// Role split with 1-step skew: half0 lane j = L0(t) row j; half1 lane j =
// L1(t-1) row j.  h0 broadcast via v_readlane; h1 via LDS round trip.
// Round-5: staging loop software-pipelined (batched global loads).
// Round-8: (a) every xor-32 reduce uses v_permlane32_swap (VALU) instead of
// ds_bpermute -- the per-step lgkm queue carries only the h1 exchange;
// (b) step reordered A-dots -> B-dots -> R so the h1 write+read round trip
// (issued at the end of the previous step) completes under the ~192cy A-dot
// issue stream instead of under the ~64cy readlane transport.
// ---------------------------------------------------------------------------
__global__ __launch_bounds__(64, 1)
void moe_gru_kernel(const float* __restrict__ x,
                    const int*   __restrict__ horizon,
                    const float* __restrict__ emb,
                    const float* __restrict__ W_gate,
                    const float* __restrict__ b_gate,
                    const float* __restrict__ b_in,
                    const float* __restrict__ Wih0,
                    const float* __restrict__ Whh0,
                    const float* __restrict__ bih0,
                    const float* __restrict__ bhh0,
                    const float* __restrict__ Wih1,
                    const float* __restrict__ Whh1,
                    const float* __restrict__ bih1,
                    const float* __restrict__ bhh1,
                    const float* __restrict__ Wh1,
                    const float* __restrict__ bh1,
                    const float* __restrict__ Wh2,
                    const float* __restrict__ bh2,
                    const float* __restrict__ Cg,
                    float* __restrict__ out) {
    __shared__ __align__(16) float smem[4800 + 3600 + 64 + 64 + 32];
    float* CT  = smem;                  // [f][96] folded xg0 weights
    float* xs  = smem + 4800;           // [f][CHUNK] transposed x chunk
    float* heL = smem + 4800 + 3600;    // 64: h_embed
    float* bbL = heL + 64;              // 64: b_in + h_embed
    float* h1L = bbL + 64;              // 32: h1 exchange + final h1 for head

    const int bid = blockIdx.x;
    const int b   = bid >> 2;
    const int e   = bid & 3;
    const int tid = threadIdx.x;
    const int j   = tid & 31;
    const int hlf = tid >> 5;
    const int k0h = hlf << 4;

    // ---- stage h_embed / (b_in + h_embed) (wave-synchronous) ----
    {
        int hor = horizon[b];
        float he = emb[(size_t)hor * ND + tid];
        heL[tid] = he;
        bbL[tid] = he + b_in[tid];
    }

    // ---- gating (every thread computes identically) ----
    float lg[NE];
    #pragma unroll
    for (int q = 0; q < NE; q++) {
        float s = b_gate[q];
        for (int d = 0; d < ND; d++) s += heL[d] * W_gate[q * ND + d];
        lg[q] = s;
    }
    int i1 = 0;
    #pragma unroll
    for (int q = 1; q < NE; q++) if (lg[q] > lg[i1]) i1 = q;
    int i2 = (i1 == 0) ? 1 : 0;
    #pragma unroll
    for (int q = 0; q < NE; q++) if (q != i1 && lg[q] > lg[i2]) i2 = q;
    if (e != i1 && e != i2) return;          // block-uniform
    const float ex2 = expf(lg[i2] - lg[i1]);
    const float wgt = (e == i1) ? (1.f / (1.f + ex2)) : (ex2 / (1.f + ex2));

    // ---- stage folded xg0 weights into LDS ----
    for (int idx = tid; idx < NF * G3; idx += 64)
        CT[idx] = Cg[(size_t)e * NF * G3 + idx];

    // ---- per-lane weights ----
    // selA: half0 -> Whh0 rows {j, j+32, j+64}; half1 -> Wih1 rows (full 32-k)
    v2f sA0[16], sA1[16], sA2[16];
    // wB: Whh1 rows {j, j+32, j+64}, k-half [k0h, k0h+16)
    v2f wB0[8], wB1[8], wB2[8];
    {
        const float* baseA = (hlf ? Wih1 : Whh0) + (size_t)e * G3 * NH;
        const float* rA0 = baseA + (size_t)j * NH;
        const float* rA1 = baseA + (size_t)(j + 32) * NH;
        const float* rA2 = baseA + (size_t)(j + 64) * NH;
        #pragma unroll
        for (int q4 = 0; q4 < 8; q4++) {
            float4 qa = ((const float4*)rA0)[q4];
            sA0[2*q4] = mkv2(qa.x, qa.y); sA0[2*q4+1] = mkv2(qa.z, qa.w);
            float4 qb = ((const float4*)rA1)[q4];
            sA1[2*q4] = mkv2(qb.x, qb.y); sA1[2*q4+1] = mkv2(qb.z, qb.w);
            float4 qc = ((const float4*)rA2)[q4];
            sA2[2*q4] = mkv2(qc.x, qc.y); sA2[2*q4+1] = mkv2(qc.z, qc.w);
        }
        const float* baseB = Whh1 + (size_t)e * G3 * NH;
        const float* rB0 = baseB + (size_t)j * NH + k0h;
        const float* rB1 = baseB + (size_t)(j + 32) * NH + k0h;
        const float* rB2 = baseB + (size_t)(j + 64) * NH + k0h;
        #pragma unroll
        for (int q4 = 0; q4 < 4; q4++) {
            float4 qa = ((const float4*)rB0)[q4];
            wB0[2*q4] = mkv2(qa.x, qa.y); wB0[2*q4+1] = mkv2(qa.z, qa.w);
            float4 qb = ((const float4*)rB1)[q4];
            wB1[2*q4] = mkv2(qb.x, qb.y); wB1[2*q4+1] = mkv2(qb.z, qb.w);
            float4 qc = ((const float4*)rB2)[q4];
            wB2[2*q4] = mkv2(qc.x, qc.y); wB2[2*q4+1] = mkv2(qc.z, qc.w);
        }
    }
    const float selb0 = hlf ? bih1[e*G3 + j]      : bhh0[e*G3 + j];
    const float selb1 = hlf ? bih1[e*G3 + j + 32] : bhh0[e*G3 + j + 32];
    const float selb2 = hlf ? bih1[e*G3 + j + 64] : bhh0[e*G3 + j + 64];
    const float whb0  = hlf ? 0.f : bhh1[e*G3 + j];
    const float whb1  = hlf ? 0.f : bhh1[e*G3 + j + 32];
    const float whb2  = hlf ? 0.f : bhh1[e*G3 + j + 64];

    // dreg = bih0 + Wih0 @ (b_in + h_embed), added once (half0 side of reduce)
    float dreg0, dreg1, dreg2;
    {
        float s0 = bih0[e*G3 + j], s1 = bih0[e*G3 + j + 32], s2 = bih0[e*G3 + j + 64];
        const float* w0 = Wih0 + ((size_t)e * G3 + j) * ND;
        const float* w1 = Wih0 + ((size_t)e * G3 + j + 32) * ND;
        const float* w2 = Wih0 + ((size_t)e * G3 + j + 64) * ND;
        for (int d = 0; d < ND; d++) {
            float bb = bbL[d];
            s0 += w0[d] * bb; s1 += w1[d] * bb; s2 += w2[d] * bb;
        }
        dreg0 = hlf ? 0.f : s0;
        dreg1 = hlf ? 0.f : s1;
        dreg2 = hlf ? 0.f : s2;
    }

    // ---- pipeline state ----
    v2f h0v[16], h1v[8];
    #pragma unroll
    for (int k = 0; k < 16; k++) h0v[k] = splat2(0.f);
    #pragma unroll
    for (int k = 0; k < 8; k++)  h1v[k] = splat2(0.f);
    float hold = 0.f;                    // half0: h0_j ; half1: h1_j (skewed)
    float lmul = hlf ? 0.f : 1.f;        // neutralizes the fake first L1 step
    if (tid < 32) h1L[tid] = 0.f;

    const float* xg = x + (size_t)b * LSEQ * NF;

    for (int ch = 0; ch < NCHUNK; ch++) {
        // ---- stage x chunk: software-pipelined (batched loads, then
        // transpose-writes).  (CHUNK*NF)/4 = 900 float4s; u=0..13 covers
        // i4 = tid + 64u <= 895, remainder 896..899 handled by tid < 4. ----
        {
            const float4* xc4 = (const float4*)(xg + (size_t)ch * CHUNK * NF);
            float4 vb[7];
            // batch 1: issue 7 loads, then write
            #pragma unroll
            for (int u = 0; u < 7; u++) vb[u] = xc4[tid + 64 * u];
            #pragma unroll
            for (int u = 0; u < 7; u++) {
                int idx = (tid + 64 * u) * 4;
                #pragma unroll
                for (int uu = 0; uu < 4; uu++) {
                    int id = idx + uu;
                    int it = (int)(((unsigned)id * 5243u) >> 18);   // id/50
                    int f  = id - it * 50;
                    float val = (uu == 0) ? vb[u].x : (uu == 1) ? vb[u].y
                              : (uu == 2) ? vb[u].z : vb[u].w;
                    xs[f * CHUNK + it] = val;
                }
            }
            // batch 2: issue 7 loads, then write
            #pragma unroll
            for (int u = 0; u < 7; u++) vb[u] = xc4[tid + 64 * (u + 7)];
            #pragma unroll
            for (int u = 0; u < 7; u++) {
                int idx = (tid + 64 * (u + 7)) * 4;
                #pragma unroll
                for (int uu = 0; uu < 4; uu++) {
                    int id = idx + uu;
                    int it = (int)(((unsigned)id * 5243u) >> 18);   // id/50
                    int f  = id - it * 50;
                    float val = (uu == 0) ? vb[u].x : (uu == 1) ? vb[u].y
                              : (uu == 2) ? vb[u].z : vb[u].w;
                    xs[f * CHUNK + it] = val;
                }
            }
            // remainder: i4 = 896..899
            if (tid < 4) {
                float4 v = xc4[896 + tid];
                int idx = (896 + tid) * 4;
                #pragma unroll
                for (int uu = 0; uu < 4; uu++) {
                    int id = idx + uu;
                    int it = (int)(((unsigned)id * 5243u) >> 18);   // id/50
                    int f  = id - it * 50;
                    float val = (uu == 0) ? v.x : (uu == 1) ? v.y
                              : (uu == 2) ? v.z : v.w;
                    xs[f * CHUNK + it] = val;
                }
            }
        }

        for (int blk = 0; blk < NBLK; blk++) {
            const int ib0 = blk * TBLK;
            // ---- xg0 partials for TBLK steps (f-split across halves) ----
            v2f a0[4], a1[4], a2[4];
            #pragma unroll
            for (int p = 0; p < 4; p++) {
                a0[p] = splat2(dreg0); a1[p] = splat2(dreg1); a2[p] = splat2(dreg2);
            }
            {
                const int fb = 25 * hlf;
                #pragma unroll 5
                for (int f = 0; f < 25; f++) {
                    const int fg = fb + f;
                    float c0 = CT[fg * G3 + j];
                    float c1 = CT[fg * G3 + j + 32];
                    float c2 = CT[fg * G3 + j + 64];
                    const float4* xp = (const float4*)(xs + fg * CHUNK + ib0);
                    float4 xa = xp[0], xb = xp[1];
                    v2f xv[4] = { mkv2(xa.x, xa.y), mkv2(xa.z, xa.w),
                                  mkv2(xb.x, xb.y), mkv2(xb.z, xb.w) };
                    v2f w0 = splat2(c0), w1 = splat2(c1), w2 = splat2(c2);
                    #pragma unroll
                    for (int p = 0; p < 4; p++) {
                        a0[p] = v2fma(w0, xv[p], a0[p]);
                        a1[p] = v2fma(w1, xv[p], a1[p]);
                        a2[p] = v2fma(w2, xv[p], a2[p]);
                    }
                }
            }
            // cross-half reduce of xg0 (VALU permlane; no lgkm queue traffic)
            #pragma unroll
            for (int p = 0; p < 4; p++) {
                a0[p].x = xor32sum(a0[p].x); a0[p].y = xor32sum(a0[p].y);
                a1[p].x = xor32sum(a1[p].x); a1[p].y = xor32sum(a1[p].y);
                a2[p].x = xor32sum(a2[p].x); a2[p].y = xor32sum(a2[p].y);
            }

            // ---- TBLK pipelined steps: L0(t) on half0 || L1(t-1) on half1 ----
            #pragma unroll
            for (int i = 0; i < TBLK; i++) {
                // A-dots first: 96-instr issue stream over h0v covers the h1
                // LDS round trip issued at the end of the previous step.
                v2f dA0 = mkv2(selb0, 0.f), dA1 = mkv2(selb1, 0.f), dA2 = mkv2(selb2, 0.f);
                #pragma unroll
                for (int k = 0; k < 16; k++) {
                    dA0 = v2fma(sA0[k], h0v[k], dA0);
                    dA1 = v2fma(sA1[k], h0v[k], dA1);
                    dA2 = v2fma(sA2[k], h0v[k], dA2);
                }
                float A0 = dA0.x + dA0.y, A1 = dA1.x + dA1.y, A2 = dA2.x + dA2.y;
                // B-dots (k-half over h1 from LDS)
                v2f dB0 = mkv2(whb0, 0.f), dB1 = mkv2(whb1, 0.f), dB2 = mkv2(whb2, 0.f);
                #pragma unroll
                for (int k = 0; k < 8; k++) {
                    dB0 = v2fma(wB0[k], h1v[k], dB0);
                    dB1 = v2fma(wB1[k], h1v[k], dB1);
                    dB2 = v2fma(wB2[k], h1v[k], dB2);
                }
                // xor-32 reduce via permlane: pure VALU, nothing exposed
                float R0 = xor32sum(dB0.x + dB0.y);
                float R1 = xor32sum(dB1.x + dB1.y);
                float R2 = xor32sum(dB2.x + dB2.y);
                const float ac0 = a0[i >> 1][i & 1];
                const float ac1 = a1[i >> 1][i & 1];
                const float ac2 = a2[i >> 1][i & 1];
                // gate assembly (uniform instructions, per-half operand select)
                float o0   = hlf ? R0 : ac0;
                float o1   = hlf ? R1 : ac1;
                float npre = hlf ? A2 : ac2;
                float gn   = hlf ? R2 : A2;
                float r = fsig(A0 + o0);
                float z = fsig(A1 + o1);
                float n = ftanh(npre + r * gn);
                float hnew = (n + z * (hold - n)) * lmul;
                hold = hnew;
                lmul = 1.f;
                // h1 exchange via LDS; round trip covered by next step's A-dots
                if (hlf) h1L[j] = hnew;
                const float4* h1q = (const float4*)(h1L + k0h);
                float4 q0 = h1q[0], q1 = h1q[1], q2 = h1q[2], q3 = h1q[3];
                h1v[0] = mkv2(q0.x, q0.y); h1v[1] = mkv2(q0.z, q0.w);
                h1v[2] = mkv2(q1.x, q1.y); h1v[3] = mkv2(q1.z, q1.w);
                h1v[4] = mkv2(q2.x, q2.y); h1v[5] = mkv2(q2.z, q2.w);
                h1v[6] = mkv2(q3.x, q3.y); h1v[7] = mkv2(q3.z, q3.w);
                // h0 broadcast via v_readlane: VALU-only, no DS latency
                {
                    int hni = __float_as_int(hnew);
                    #pragma unroll
                    for (int k = 0; k < 16; k++) {
                        float e0 = __int_as_float(__builtin_amdgcn_readlane(hni, 2*k));
                        float e1 = __int_as_float(__builtin_amdgcn_readlane(hni, 2*k+1));
                        h0v[k] = mkv2(e0, e1);
                    }
                }
            }
        }
    }

    // ---- epilogue: L1(LSEQ-1) (results used from half1 only) ----
    {
        v2f dA0 = mkv2(selb0, 0.f), dA1 = mkv2(selb1, 0.f), dA2 = mkv2(selb2, 0.f);
        #pragma unroll
        for (int k = 0; k < 16; k++) {
            dA0 = v2fma(sA0[k], h0v[k], dA0);
            dA1 = v2fma(sA1[k], h0v[k], dA1);
            dA2 = v2fma(sA2[k], h0v[k], dA2);
        }
        v2f dB0 = mkv2(whb0, 0.f), dB1 = mkv2(whb1, 0.f), dB2 = mkv2(whb2, 0.f);
        #pragma unroll
        for (int k = 0; k < 8; k++) {
            dB0 = v2fma(wB0[k], h1v[k], dB0);
            dB1 = v2fma(wB1[k], h1v[k], dB1);
            dB2 = v2fma(wB2[k], h1v[k], dB2);
        }
        float A0 = dA0.x + dA0.y, A1 = dA1.x + dA1.y, A2 = dA2.x + dA2.y;
        float R0 = xor32sum(dB0.x + dB0.y);
        float R1 = xor32sum(dB1.x + dB1.y);
        float R2 = xor32sum(dB2.x + dB2.y);
        float r = fsig(A0 + R0);
        float z = fsig(A1 + R1);
        float n = ftanh(A2 + r * R2);
        float hfin = n + z * (hold - n);
        if (hlf) h1L[j] = hfin;
    }

    // ---- head MLP + weighted accumulation ----
    if (tid < 32) {
        float s = bh1[e * NHU + tid];
        const float* wr = Wh1 + ((size_t)e * NHU + tid) * NH;
        #pragma unroll
        for (int d = 0; d < NH; d++) s += wr[d] * h1L[d];
        float hid = fmaxf(s, 0.f);
        float c = hid * Wh2[e * NHU + tid];
        #pragma unroll
        for (int off = 16; off > 0; off >>= 1) c += __shfl_down(c, off, 64);
        if (tid == 0) atomicAdd(out + b, wgt * (c + bh2[e]));
    }
}

extern "C" void kernel_launch(void* const* d_in, const int* in_sizes, int n_in,
                              void* d_out, int out_size, void* d_ws, size_t ws_size,
                              hipStream_t stream) {
    const float* x       = (const float*)d_in[0];
    const int*   horizon = (const int*)  d_in[1];
    const float* W_in    = (const float*)d_in[2];
    const float* b_in    = (const float*)d_in[3];
    const float* emb     = (const float*)d_in[4];
    const float* W_gate  = (const float*)d_in[5];
    const float* b_gate  = (const float*)d_in[6];
    const float* Wih0    = (const float*)d_in[7];
    const float* Whh0    = (const float*)d_in[8];
    const float* bih0    = (const float*)d_in[9];
    const float* bhh0    = (const float*)d_in[10];
    const float* Wih1    = (const float*)d_in[11];
    const float* Whh1    = (const float*)d_in[12];
    const float* bih1    = (const float*)d_in[13];
    const float* bhh1    = (const float*)d_in[14];
    const float* Wh1     = (const float*)d_in[15];
    const float* bh1     = (const float*)d_in[16];
    const float* Wh2     = (const float*)d_in[17];
    const float* bh2     = (const float*)d_in[18];
    float* out = (float*)d_out;
    float* Cg  = (float*)d_ws;   // NE*NF*G3 floats = 76.8 KB

    hipMemsetAsync(d_out, 0, NB * sizeof(float), stream);
    compute_C_kernel<<<dim3(NE), dim3(256), 0, stream>>>(Wih0, W_in, Cg);
    moe_gru_kernel<<<dim3(NB * NE), dim3(64), 0, stream>>>(
        x, horizon, emb, W_gate, b_gate, b_in,
        Wih0, Whh0, bih0, bhh0, Wih1, Whh1, bih1, bhh1,
        Wh1, bh1, Wh2, bh2, Cg, out);
}